// Round 7
// baseline (242.494 us; speedup 1.0000x reference)
//
#include <hip/hip_runtime.h>

#define S_LEN 2048
#define D_DIM 1024
#define NH    16
#define HD    64
#define BATCH 4
#define M_ROWS 8192

typedef __attribute__((ext_vector_type(8))) short bf16x8;   // 8 bf16 = 4 VGPR
typedef __attribute__((ext_vector_type(4))) float f32x4;
typedef __attribute__((ext_vector_type(16))) float f32x16;
typedef __attribute__((ext_vector_type(8))) unsigned short u16x8;

__device__ __forceinline__ unsigned short f2bf(float f) {
    unsigned u = __builtin_bit_cast(unsigned, f);
    u = (u + 0x7fffu + ((u >> 16) & 1u)) >> 16;   // RNE
    return (unsigned short)u;
}

__device__ __forceinline__ void gload16(const void* g, void* l) {
    __builtin_amdgcn_global_load_lds((const __attribute__((address_space(1))) unsigned*)g,
                                     (__attribute__((address_space(3))) unsigned*)l,
                                     16, 0, 0);
}

template<int N> __device__ __forceinline__ void vmwait() {
    if constexpr (N == 0)      asm volatile("s_waitcnt vmcnt(0)" ::: "memory");
    else if constexpr (N == 3) asm volatile("s_waitcnt vmcnt(3)" ::: "memory");
    else if constexpr (N == 5) asm volatile("s_waitcnt vmcnt(5)" ::: "memory");
}

// pack two f32 -> bf16x2 (RNE) in one instruction
__device__ __forceinline__ unsigned cvtpk_bf16(float lo, float hi) {
    unsigned r;
    asm("v_cvt_pk_bf16_f32 %0, %1, %2" : "=v"(r) : "v"(lo), "v"(hi));
    return r;
}
// swap a[32:63] <-> b[0:31] (both operands updated)
__device__ __forceinline__ void pl32swap(unsigned &a, unsigned &b) {
    asm("v_permlane32_swap_b32 %0, %1" : "+v"(a), "+v"(b));
}

// ---------------------------------------------------------------------------
// Merged prep: blocks [0,4096) cast x fp32->bf16; blocks [4096,5120) build
// W^T bf16 (wq pre-scaled by 0.125*log2(e)). One launch instead of two.
// ---------------------------------------------------------------------------
__global__ __launch_bounds__(256) void prep_k(const float* __restrict__ x,
                                              const float* __restrict__ w0, const float* __restrict__ w1,
                                              const float* __restrict__ w2, const float* __restrict__ w3,
                                              unsigned short* __restrict__ xbf,
                                              unsigned short* __restrict__ o0, unsigned short* __restrict__ o1,
                                              unsigned short* __restrict__ o2, unsigned short* __restrict__ o3) {
    __shared__ float sT[64][65];
    const int t = threadIdx.x;
    if (blockIdx.x < 4096) {
        size_t i = (size_t)blockIdx.x * 256 + t;
        const float4* xf = (const float4*)x;
        float4 a = xf[2 * i], b = xf[2 * i + 1];
        u16x8 v;
        v[0] = f2bf(a.x); v[1] = f2bf(a.y); v[2] = f2bf(a.z); v[3] = f2bf(a.w);
        v[4] = f2bf(b.x); v[5] = f2bf(b.y); v[6] = f2bf(b.z); v[7] = f2bf(b.w);
        *(u16x8*)(xbf + i * 8) = v;
        return;
    }
    const int wb = blockIdx.x - 4096;          // 0..1023
    const int z = wb >> 8;                     // weight index
    const float* w; unsigned short* o;
    switch (z) {
        case 0: w = w0; o = o0; break;
        case 1: w = w1; o = o1; break;
        case 2: w = w2; o = o2; break;
        default: w = w3; o = o3; break;
    }
    const float sc = (z == 0) ? 0.18033688011112042f : 1.0f;
    const int n0 = (wb & 15) * 64, k0 = ((wb >> 4) & 15) * 64;
    const int r = t >> 4, cq = t & 15;
#pragma unroll
    for (int it = 0; it < 4; ++it) {
        int k = r + it * 16;
        float4 v = *(const float4*)&w[(size_t)(k0 + k) * D_DIM + n0 + cq * 4];
        sT[k][cq * 4 + 0] = v.x; sT[k][cq * 4 + 1] = v.y;
        sT[k][cq * 4 + 2] = v.z; sT[k][cq * 4 + 3] = v.w;
    }
    __syncthreads();
    const int n = t >> 2, ch = t & 3;
    union { unsigned short s[8]; uint4 v; } p0, p1;
#pragma unroll
    for (int j = 0; j < 8; ++j) p0.s[j] = f2bf(sT[ch * 16 + j][n] * sc);
#pragma unroll
    for (int j = 0; j < 8; ++j) p1.s[j] = f2bf(sT[ch * 16 + 8 + j][n] * sc);
    *(uint4*)&o[(size_t)(n0 + n) * D_DIM + k0 + ch * 16]     = p0.v;
    *(uint4*)&o[(size_t)(n0 + n) * D_DIM + k0 + ch * 16 + 8] = p1.v;
}

// ---------------------------------------------------------------------------
// Fine-phase GEMM core. Tile = (MFRAG*32) x (NFRAG*64), BK=32. 8 waves as
// 2M x 4N: per-wave output = MFRAG*16 rows x NFRAG*16 cols, acc[MFRAG][NFRAG].
// 3-slot LDS ring, 1 full tile always in flight across barriers (T4).
// XOR chunk swizzle both sides -> measured 0 bank conflicts (R2-R6).
// ---------------------------------------------------------------------------
template<int MFRAG, int NFRAG, int AGLD, int BGLD>
__device__ __forceinline__ void gemm_core(const unsigned short* __restrict__ A,
                                          const unsigned short* __restrict__ Bt,
                                          unsigned short* __restrict__ sA,
                                          unsigned short* __restrict__ sB,
                                          int m0, int n0, int t,
                                          f32x4 (&acc)[MFRAG][NFRAG])
{
    constexpr int NGLD  = AGLD + BGLD;
    constexpr int ASLOT = AGLD * 4096;     // elems per ring slot
    constexpr int BSLOT = BGLD * 4096;
    constexpr int NPH   = MFRAG / 2;       // phases per K-32 tile

    const int lane = t & 63, wid = t >> 6;
    const int mm = lane & 15, quad = lane >> 4;
    const int wm = wid >> 2, wn = wid & 3;

    const int sr = t >> 2;
    const int sg = (t & 3) ^ ((sr >> 1) & 3);
    const unsigned short* asrc = A  + (size_t)(m0 + sr) * D_DIM + sg * 8;
    const unsigned short* bsrc = Bt + (size_t)(n0 + sr) * D_DIM + sg * 8;
    unsigned short* dA = sA + t * 8;
    unsigned short* dB = sB + t * 8;

    const int al = wm * (MFRAG * 16) + mm;
    const int bl = wn * (NFRAG * 16) + mm;
    const int xs = quad ^ ((mm >> 1) & 3);

    // prologue: tiles 0,1 into slots 0,1; confirm tile 0, keep tile 1 in flight
#pragma unroll
    for (int pt = 0; pt < 2; ++pt) {
        const int ko = pt * 32;
#pragma unroll
        for (int i = 0; i < AGLD; ++i)
            gload16(asrc + (size_t)i * 128 * D_DIM + ko, dA + pt * ASLOT + i * 4096);
#pragma unroll
        for (int i = 0; i < BGLD; ++i)
            gload16(bsrc + (size_t)i * 128 * D_DIM + ko, dB + pt * BSLOT + i * 4096);
    }
    vmwait<NGLD>();
    __builtin_amdgcn_s_barrier();

    int sRead = 0, sWrite = 2;
    for (int T = 0; T < 32; ++T) {
        const int soA = sRead * ASLOT, soB = sRead * BSLOT;
        const int woA = sWrite * ASLOT, woB = sWrite * BSLOT;
        const int ko = (T + 2) * 32;
        const bool st = (T <= 29);

        bf16x8 bv[NFRAG];
#pragma unroll
        for (int p = 0; p < NPH; ++p) {
            if (p == 0) {
#pragma unroll
                for (int nf = 0; nf < NFRAG; ++nf)
                    bv[nf] = *(const bf16x8*)&sB[soB + (bl + nf * 16) * 32 + xs * 8];
            }
            bf16x8 af0 = *(const bf16x8*)&sA[soA + (al + (2 * p) * 16) * 32 + xs * 8];
            bf16x8 af1 = *(const bf16x8*)&sA[soA + (al + (2 * p + 1) * 16) * 32 + xs * 8];

            if (st) {
                if (p == 0) {
#pragma unroll
                    for (int i = 0; i < AGLD; ++i)
                        gload16(asrc + (size_t)i * 128 * D_DIM + ko, dA + woA + i * 4096);
                } else {
#pragma unroll
                    for (int i = 0; i < BGLD; ++i)
                        if ((i % (NPH - 1)) == p - 1)
                            gload16(bsrc + (size_t)i * 128 * D_DIM + ko, dB + woB + i * 4096);
                }
            }

            __builtin_amdgcn_s_barrier();
            asm volatile("s_waitcnt lgkmcnt(0)" ::: "memory");
            __builtin_amdgcn_s_setprio(1);
#pragma unroll
            for (int nf = 0; nf < NFRAG; ++nf) {
                acc[2 * p][nf]     = __builtin_amdgcn_mfma_f32_16x16x32_bf16(af0, bv[nf], acc[2 * p][nf], 0, 0, 0);
                acc[2 * p + 1][nf] = __builtin_amdgcn_mfma_f32_16x16x32_bf16(af1, bv[nf], acc[2 * p + 1][nf], 0, 0, 0);
            }
            __builtin_amdgcn_s_setprio(0);
            if (p == NPH - 1) {
                if (T <= 29)      vmwait<NGLD>();   // tile T+1 confirmed, T+2 in flight
                else if (T == 30) vmwait<0>();      // drain: tile 31 confirmed
            }
            __builtin_amdgcn_s_barrier();
        }

        sRead  = (sRead  == 2) ? 0 : sRead + 1;
        sWrite = (sWrite == 2) ? 0 : sWrite + 1;
    }
}

// ---------------------------------------------------------------------------
// Fused QKV GEMM: BM=256, BN=384 -> grid 32m x 8n = 256 blocks = 1.0 exact
// round, 153.6 FLOP/staged-byte. B^T = [Wq^T|Wk^T|Wv^T] contiguous; epilogue
// routes per 16-wide fragment. LDS 120KB (3-slot ring). XCD chunking:
// 4 m-tiles x all n per XCD -> A panel 2MB L2-resident.
// ---------------------------------------------------------------------------
__global__ __launch_bounds__(512, 2) void gemmqkv_k(const unsigned short* __restrict__ A,
                                                    const unsigned short* __restrict__ Bt,
                                                    unsigned short* __restrict__ qb,
                                                    unsigned short* __restrict__ kb,
                                                    unsigned short* __restrict__ vt)
{
    __shared__ unsigned short sA[3 * 2 * 4096];    // 48KB
    __shared__ unsigned short sB[3 * 3 * 4096];    // 72KB
    const int t = threadIdx.x;
    const int bid = blockIdx.x;                    // 256 = 8 XCD * 32
    const int wg = (bid & 7) * 32 + (bid >> 3);
    const int mt = wg >> 3, nt = wg & 7;
    const int m0 = mt * 256, n0 = nt * 384;

    f32x4 acc[8][6];
#pragma unroll
    for (int i = 0; i < 8; ++i)
#pragma unroll
        for (int j = 0; j < 6; ++j) acc[i][j] = (f32x4){0.f, 0.f, 0.f, 0.f};

    gemm_core<8, 6, 2, 3>(A, Bt, sA, sB, m0, n0, t, acc);

    const int lane = t & 63, wid = t >> 6;
    const int mm = lane & 15, quad = lane >> 4;
    const int wm = wid >> 2, wn = wid & 3;

#pragma unroll
    for (int nf = 0; nf < 6; ++nf) {
        const int c0 = n0 + wn * 96 + nf * 16;     // 16-aligned -> widx uniform
        const int widx = c0 >> 10, nl0 = c0 & 1023;
        if (widx == 2) {
            // V: write transposed per head (16-wide frag never crosses a head)
            const int h = nl0 >> 6, hd = (nl0 & 63) + mm;
#pragma unroll
            for (int mf = 0; mf < 8; ++mf) {
                int rglob = m0 + wm * 128 + mf * 16 + quad * 4;
                int bb = rglob >> 11, ss = rglob & (S_LEN - 1);
                union { unsigned short s[4]; unsigned long long ll; } pk;
#pragma unroll
                for (int r = 0; r < 4; ++r) pk.s[r] = f2bf(acc[mf][nf][r]);
                *(unsigned long long*)&vt[((size_t)(bb * NH + h) * HD + hd) * S_LEN + ss] = pk.ll;
            }
        } else {
            unsigned short* outp = widx ? kb : qb;
#pragma unroll
            for (int mf = 0; mf < 8; ++mf)
#pragma unroll
                for (int r = 0; r < 4; ++r)
                    outp[(size_t)(m0 + wm * 128 + mf * 16 + quad * 4 + r) * D_DIM +
                         nl0 + mm] = f2bf(acc[mf][nf][r]);
        }
    }
}

// ---------------------------------------------------------------------------
// Output GEMM: out_fp32 = ctx_bf16 * WoT^T. BM=128, BN=256 -> 64m x 4n =
// 256 blocks = 1.0 exact round. Same fine-phase core (2 phases x 8 MFMA).
// XCD chunking 8m x 4n: A 2MB + B 2MB both L2-resident per XCD.
// ---------------------------------------------------------------------------
__global__ __launch_bounds__(512, 2) void gemmo_k(const unsigned short* __restrict__ A,
                                                  const unsigned short* __restrict__ Bt,
                                                  float* __restrict__ C)
{
    __shared__ unsigned short sA[3 * 4096];        // 24KB
    __shared__ unsigned short sB[3 * 2 * 4096];    // 48KB
    const int t = threadIdx.x;
    const int bid = blockIdx.x;                    // 256 = 8 XCD * 32
    const int wg = (bid & 7) * 32 + (bid >> 3);
    const int mt = wg >> 2, nt = wg & 3;
    const int m0 = mt * 128, n0 = nt * 256;

    f32x4 acc[4][4];
#pragma unroll
    for (int i = 0; i < 4; ++i)
#pragma unroll
        for (int j = 0; j < 4; ++j) acc[i][j] = (f32x4){0.f, 0.f, 0.f, 0.f};

    gemm_core<4, 4, 1, 2>(A, Bt, sA, sB, m0, n0, t, acc);

    const int lane = t & 63, wid = t >> 6;
    const int mm = lane & 15, quad = lane >> 4;
    const int wm = wid >> 2, wn = wid & 3;

#pragma unroll
    for (int mf = 0; mf < 4; ++mf)
#pragma unroll
        for (int nf = 0; nf < 4; ++nf)
#pragma unroll
            for (int r = 0; r < 4; ++r)
                C[(size_t)(m0 + wm * 64 + mf * 16 + quad * 4 + r) * D_DIM +
                  n0 + wn * 64 + nf * 16 + mm] = acc[mf][nf][r];
}

// ---------------------------------------------------------------------------
// Fused causal flash attention: 32x32x16 MFMA + in-register P (T12 cvt_pk +
// permlane32_swap), QBLK=256 (8 waves x 32 q-rows). R6 lesson: with 4-wave
// blocks the per-tile chain ran serial (1 wave of the block per SIMD) and the
// uniform block length made the WHOLE kernel = one block's chain (4842
// cy/tile). 8-wave blocks put 2 same-block waves per SIMD working the same
// tile -> tile period ~ LDS floor (~2000cy) instead of chain (R5 evidence:
// 1266 cy/tile at 8 waves). Pairs (qt, 7-qt) of 256-row strips -> uniform 36
// k64-tiles/block; grid 64 bh x 4 pairs = 256 blocks = 1/CU; LDS 32KB.
// bh-clustered XCD map (R6-verified: FETCH 146MB -> 24.6MB).
// Staging: 512 thr = one gload16 per 64x64 plane. Swapped QK^T (A=K, B=Q);
// P-frags built in regs (16 cvt_pk + 8 permlane); PV: O^T = V^T P^T;
// l via ones-A MFMA (same quantized P as PV).
// ---------------------------------------------------------------------------
__global__ __launch_bounds__(512, 2) void attn_k(const unsigned short* __restrict__ Q,
                                                 const unsigned short* __restrict__ K,
                                                 const unsigned short* __restrict__ Vt,
                                                 unsigned short* __restrict__ ctx)
{
    __shared__ unsigned short sK [2][64 * 64];   // [buf][key][hd]   2x8KB
    __shared__ unsigned short sVT[2][64 * 64];   // [buf][hd][key]   2x8KB
    const int t = threadIdx.x;
    const int lane = t & 63, w = t >> 6;          // w = 0..7
    const int m5 = lane & 31, h = lane >> 5;
    const int m7 = m5 & 7;
    const int bid = blockIdx.x;                   // 256
    const int xcd = bid & 7, ii = bid >> 3;       // ii 0..31
    const int bh = xcd * 8 + (ii >> 2);           // 8 bh per XCD (4MB K/V -> L2)
    const int pair = ii & 3;                      // 0..3
    const int b = bh >> 4, hh = bh & 15;
    const size_t rowbase = (size_t)b * S_LEN;
    const int coff = hh * HD;
    const unsigned short* Vh = Vt + (size_t)bh * HD * S_LEN;

    // staging: 512 threads cover one 64-row x 128B plane; XOR chunk swizzle
    const int sc = t >> 3, sj = t & 7;
    const int sg = (sj ^ (sc & 7)) * 8;

    u16x8 onesu;
#pragma unroll
    for (int j = 0; j < 8; ++j) onesu[j] = 0x3F80;   // bf16 1.0
    const bf16x8 ones = __builtin_bit_cast(bf16x8, onesu);

    for (int sidx = 0; sidx < 2; ++sidx) {
        const int qt = sidx ? (7 - pair) : pair;  // 256-row strip index
        const int q0 = qt * 256;
        const int qrw = q0 + w * 32;              // wave q base
        const int qr  = qrw + m5;                 // this lane's q-row (= MFMA col)

        // Q in regs: B[k=hd][col=q]: lane needs Q[qr][s*16 + h*8 + 0..7]
        bf16x8 qf[4];
#pragma unroll
        for (int s = 0; s < 4; ++s)
            qf[s] = *(const bf16x8*)(Q + (rowbase + qr) * D_DIM + coff + s * 16 + h * 8);

        f32x16 o0, o1, l16;
#pragma unroll
        for (int r = 0; r < 16; ++r) { o0[r] = 0.f; o1[r] = 0.f; l16[r] = 0.f; }

        const int nkt = 4 * qt + 4;               // k64 tiles for this strip

        // prologue: stage tile 0 -> buf 0 (one instr per plane)
        gload16(K  + (rowbase + sc) * D_DIM + coff + sg, (void*)&sK[0][t * 8]);
        gload16(Vh + (size_t)sc * S_LEN + sg,            (void*)&sVT[0][t * 8]);

        for (int kt = 0; kt < nkt; ++kt) {
            const int buf = kt & 1;
            __syncthreads();   // buf's loads drained (issued a full phase ago)
            if (kt + 1 < nkt) {
                const int k1 = (kt + 1) * 64;
                gload16(K  + (rowbase + k1 + sc) * D_DIM + coff + sg, (void*)&sK[1 - buf][t * 8]);
                gload16(Vh + (size_t)sc * S_LEN + k1 + sg,            (void*)&sVT[1 - buf][t * 8]);
            }
            const int k0 = kt * 64;
            if (k0 > qrw + 31) continue;   // fully masked for this wave

            // S^T = K Q^T : A=K rows (key = kf*32 + m5), k=hd
            f32x16 s0, s1;
#pragma unroll
            for (int r = 0; r < 16; ++r) { s0[r] = 0.f; s1[r] = 0.f; }
            __builtin_amdgcn_s_setprio(1);
#pragma unroll
            for (int s = 0; s < 4; ++s) {
                const int sl = ((2 * s + h) ^ m7) * 8;
                bf16x8 ak0 = *(const bf16x8*)&sK[buf][m5 * 64 + sl];
                bf16x8 ak1 = *(const bf16x8*)&sK[buf][(32 + m5) * 64 + sl];
                s0 = __builtin_amdgcn_mfma_f32_32x32x16_bf16(ak0, qf[s], s0, 0, 0, 0);
                s1 = __builtin_amdgcn_mfma_f32_32x32x16_bf16(ak1, qf[s], s1, 0, 0, 0);
            }
            __builtin_amdgcn_s_setprio(0);

            // p = exp2(s) (wq pre-scaled), mask, pack to PV B-frags in regs.
            // Lane reg r holds key_local = (r&3)+8*(r>>2)+4h within kf block.
            const bool needmask = (k0 + 63) > qrw;
            bf16x8 pb[4];
#pragma unroll
            for (int kf = 0; kf < 2; ++kf) {
                unsigned pw[8];
#pragma unroll
                for (int j = 0; j < 8; ++j) {
                    float plo = __builtin_amdgcn_exp2f(kf ? s1[2 * j] : s0[2 * j]);
                    float phi = __builtin_amdgcn_exp2f(kf ? s1[2 * j + 1] : s0[2 * j + 1]);
                    if (needmask) {
                        const int kb_ = k0 + kf * 32 + 4 * h;
                        const int r0 = 2 * j, r1 = 2 * j + 1;
                        if (kb_ + (r0 & 3) + 8 * (r0 >> 2) > qr) plo = 0.f;
                        if (kb_ + (r1 & 3) + 8 * (r1 >> 2) > qr) phi = 0.f;
                    }
                    pw[j] = cvtpk_bf16(plo, phi);
                }
                pl32swap(pw[0], pw[2]);
                pl32swap(pw[1], pw[3]);
                pl32swap(pw[4], pw[6]);
                pl32swap(pw[5], pw[7]);
                union { unsigned u[4]; bf16x8 v; } f0, f1;
                f0.u[0] = pw[0]; f0.u[1] = pw[1]; f0.u[2] = pw[2]; f0.u[3] = pw[3];
                f1.u[0] = pw[4]; f1.u[1] = pw[5]; f1.u[2] = pw[6]; f1.u[3] = pw[7];
                pb[kf * 2 + 0] = f0.v;
                pb[kf * 2 + 1] = f1.v;
            }

            // O^T += V^T P^T ; l += ones P^T  (same quantized P as PV)
            __builtin_amdgcn_s_setprio(1);
#pragma unroll
            for (int s = 0; s < 4; ++s) {
                const int sl = ((2 * s + h) ^ m7) * 8;
                bf16x8 vf0 = *(const bf16x8*)&sVT[buf][m5 * 64 + sl];
                bf16x8 vf1 = *(const bf16x8*)&sVT[buf][(32 + m5) * 64 + sl];
                l16 = __builtin_amdgcn_mfma_f32_32x32x16_bf16(ones, pb[s], l16, 0, 0, 0);
                o0  = __builtin_amdgcn_mfma_f32_32x32x16_bf16(vf0,  pb[s], o0, 0, 0, 0);
                o1  = __builtin_amdgcn_mfma_f32_32x32x16_bf16(vf1,  pb[s], o1, 0, 0, 0);
            }
            __builtin_amdgcn_s_setprio(0);
        }
        __syncthreads();   // all compute done before next strip's prologue restages buf0

        // normalize and store: O^T[hd][q]: reg rg*4+r -> hd = hf*32 + 8*rg + 4h + r
        const float linv = 1.f / l16[0];
#pragma unroll
        for (int hf = 0; hf < 2; ++hf) {
#pragma unroll
            for (int rg = 0; rg < 4; ++rg) {
                union { unsigned short s4[4]; unsigned long long ll; } pk4;
#pragma unroll
                for (int r = 0; r < 4; ++r)
                    pk4.s4[r] = f2bf((hf ? o1[rg * 4 + r] : o0[rg * 4 + r]) * linv);
                *(unsigned long long*)&ctx[(rowbase + qr) * D_DIM + coff + hf * 32 + 8 * rg + 4 * h] = pk4.ll;
            }
        }
    }
}

extern "C" void kernel_launch(void* const* d_in, const int* in_sizes, int n_in,
                              void* d_out, int out_size, void* d_ws, size_t ws_size,
                              hipStream_t stream)
{
    const float* x  = (const float*)d_in[0];
    const float* wq = (const float*)d_in[1];
    const float* wk = (const float*)d_in[2];
    const float* wv = (const float*)d_in[3];
    const float* wo = (const float*)d_in[4];

    const size_t XE = (size_t)M_ROWS * D_DIM;   // 8M elems
    const size_t WE = (size_t)D_DIM * D_DIM;    // 1M elems
    unsigned short* ws  = (unsigned short*)d_ws;
    unsigned short* xbf = ws;
    unsigned short* wt0 = xbf + XE;
    unsigned short* wt1 = wt0 + WE;
    unsigned short* wt2 = wt1 + WE;
    unsigned short* wt3 = wt2 + WE;
    unsigned short* qb  = wt3 + WE;
    unsigned short* kb  = qb + XE;
    unsigned short* vt  = kb + XE;      // V stored transposed per head
    unsigned short* cb  = vt + XE;      // ~80 MB total

    prep_k<<<dim3(4096 + 1024), 256, 0, stream>>>(x, wq, wk, wv, wo,
                                                  xbf, wt0, wt1, wt2, wt3);

    gemmqkv_k<<<dim3(256), 512, 0, stream>>>(xbf, wt0, qb, kb, vt);

    attn_k<<<dim3(256), 512, 0, stream>>>(qb, kb, vt, cb);

    gemmo_k<<<dim3(256), 512, 0, stream>>>(cb, wt3, (float*)d_out);
}

// Round 8
// 238.369 us; speedup vs baseline: 1.0173x; 1.0173x over previous
//
#include <hip/hip_runtime.h>

#define S_LEN 2048
#define D_DIM 1024
#define NH    16
#define HD    64
#define BATCH 4
#define M_ROWS 8192

typedef __attribute__((ext_vector_type(8))) short bf16x8;   // 8 bf16 = 4 VGPR
typedef __attribute__((ext_vector_type(4))) float f32x4;
typedef __attribute__((ext_vector_type(16))) float f32x16;
typedef __attribute__((ext_vector_type(8))) unsigned short u16x8;

__device__ __forceinline__ unsigned short f2bf(float f) {
    unsigned u = __builtin_bit_cast(unsigned, f);
    u = (u + 0x7fffu + ((u >> 16) & 1u)) >> 16;   // RNE
    return (unsigned short)u;
}

__device__ __forceinline__ void gload16(const void* g, void* l) {
    __builtin_amdgcn_global_load_lds((const __attribute__((address_space(1))) unsigned*)g,
                                     (__attribute__((address_space(3))) unsigned*)l,
                                     16, 0, 0);
}

template<int N> __device__ __forceinline__ void vmwait() {
    if constexpr (N == 0)      asm volatile("s_waitcnt vmcnt(0)" ::: "memory");
    else if constexpr (N == 3) asm volatile("s_waitcnt vmcnt(3)" ::: "memory");
    else if constexpr (N == 5) asm volatile("s_waitcnt vmcnt(5)" ::: "memory");
}

// pack two f32 -> bf16x2 (RNE) in one instruction
__device__ __forceinline__ unsigned cvtpk_bf16(float lo, float hi) {
    unsigned r;
    asm("v_cvt_pk_bf16_f32 %0, %1, %2" : "=v"(r) : "v"(lo), "v"(hi));
    return r;
}
// swap a[32:63] <-> b[0:31] (both operands updated)
__device__ __forceinline__ void pl32swap(unsigned &a, unsigned &b) {
    asm("v_permlane32_swap_b32 %0, %1" : "+v"(a), "+v"(b));
}

// ---------------------------------------------------------------------------
// Merged prep: blocks [0,4096) cast x fp32->bf16; blocks [4096,5120) build
// W^T bf16 (wq pre-scaled by 0.125*log2(e)). One launch instead of two.
// ---------------------------------------------------------------------------
__global__ __launch_bounds__(256) void prep_k(const float* __restrict__ x,
                                              const float* __restrict__ w0, const float* __restrict__ w1,
                                              const float* __restrict__ w2, const float* __restrict__ w3,
                                              unsigned short* __restrict__ xbf,
                                              unsigned short* __restrict__ o0, unsigned short* __restrict__ o1,
                                              unsigned short* __restrict__ o2, unsigned short* __restrict__ o3) {
    __shared__ float sT[64][65];
    const int t = threadIdx.x;
    if (blockIdx.x < 4096) {
        size_t i = (size_t)blockIdx.x * 256 + t;
        const float4* xf = (const float4*)x;
        float4 a = xf[2 * i], b = xf[2 * i + 1];
        u16x8 v;
        v[0] = f2bf(a.x); v[1] = f2bf(a.y); v[2] = f2bf(a.z); v[3] = f2bf(a.w);
        v[4] = f2bf(b.x); v[5] = f2bf(b.y); v[6] = f2bf(b.z); v[7] = f2bf(b.w);
        *(u16x8*)(xbf + i * 8) = v;
        return;
    }
    const int wb = blockIdx.x - 4096;          // 0..1023
    const int z = wb >> 8;                     // weight index
    const float* w; unsigned short* o;
    switch (z) {
        case 0: w = w0; o = o0; break;
        case 1: w = w1; o = o1; break;
        case 2: w = w2; o = o2; break;
        default: w = w3; o = o3; break;
    }
    const float sc = (z == 0) ? 0.18033688011112042f : 1.0f;
    const int n0 = (wb & 15) * 64, k0 = ((wb >> 4) & 15) * 64;
    const int r = t >> 4, cq = t & 15;
#pragma unroll
    for (int it = 0; it < 4; ++it) {
        int k = r + it * 16;
        float4 v = *(const float4*)&w[(size_t)(k0 + k) * D_DIM + n0 + cq * 4];
        sT[k][cq * 4 + 0] = v.x; sT[k][cq * 4 + 1] = v.y;
        sT[k][cq * 4 + 2] = v.z; sT[k][cq * 4 + 3] = v.w;
    }
    __syncthreads();
    const int n = t >> 2, ch = t & 3;
    union { unsigned short s[8]; uint4 v; } p0, p1;
#pragma unroll
    for (int j = 0; j < 8; ++j) p0.s[j] = f2bf(sT[ch * 16 + j][n] * sc);
#pragma unroll
    for (int j = 0; j < 8; ++j) p1.s[j] = f2bf(sT[ch * 16 + 8 + j][n] * sc);
    *(uint4*)&o[(size_t)(n0 + n) * D_DIM + k0 + ch * 16]     = p0.v;
    *(uint4*)&o[(size_t)(n0 + n) * D_DIM + k0 + ch * 16 + 8] = p1.v;
}

// ---------------------------------------------------------------------------
// Fine-phase GEMM core. Tile = (MFRAG*32) x (NFRAG*64), BK=32. 8 waves as
// 2M x 4N: per-wave output = MFRAG*16 rows x NFRAG*16 cols, acc[MFRAG][NFRAG].
// 3-slot LDS ring, 1 full tile always in flight across barriers (T4).
// XOR chunk swizzle both sides -> measured 0 bank conflicts (R2-R7).
// ---------------------------------------------------------------------------
template<int MFRAG, int NFRAG, int AGLD, int BGLD>
__device__ __forceinline__ void gemm_core(const unsigned short* __restrict__ A,
                                          const unsigned short* __restrict__ Bt,
                                          unsigned short* __restrict__ sA,
                                          unsigned short* __restrict__ sB,
                                          int m0, int n0, int t,
                                          f32x4 (&acc)[MFRAG][NFRAG])
{
    constexpr int NGLD  = AGLD + BGLD;
    constexpr int ASLOT = AGLD * 4096;     // elems per ring slot
    constexpr int BSLOT = BGLD * 4096;
    constexpr int NPH   = MFRAG / 2;       // phases per K-32 tile

    const int lane = t & 63, wid = t >> 6;
    const int mm = lane & 15, quad = lane >> 4;
    const int wm = wid >> 2, wn = wid & 3;

    const int sr = t >> 2;
    const int sg = (t & 3) ^ ((sr >> 1) & 3);
    const unsigned short* asrc = A  + (size_t)(m0 + sr) * D_DIM + sg * 8;
    const unsigned short* bsrc = Bt + (size_t)(n0 + sr) * D_DIM + sg * 8;
    unsigned short* dA = sA + t * 8;
    unsigned short* dB = sB + t * 8;

    const int al = wm * (MFRAG * 16) + mm;
    const int bl = wn * (NFRAG * 16) + mm;
    const int xs = quad ^ ((mm >> 1) & 3);

    // prologue: tiles 0,1 into slots 0,1; confirm tile 0, keep tile 1 in flight
#pragma unroll
    for (int pt = 0; pt < 2; ++pt) {
        const int ko = pt * 32;
#pragma unroll
        for (int i = 0; i < AGLD; ++i)
            gload16(asrc + (size_t)i * 128 * D_DIM + ko, dA + pt * ASLOT + i * 4096);
#pragma unroll
        for (int i = 0; i < BGLD; ++i)
            gload16(bsrc + (size_t)i * 128 * D_DIM + ko, dB + pt * BSLOT + i * 4096);
    }
    vmwait<NGLD>();
    __builtin_amdgcn_s_barrier();

    int sRead = 0, sWrite = 2;
    for (int T = 0; T < 32; ++T) {
        const int soA = sRead * ASLOT, soB = sRead * BSLOT;
        const int woA = sWrite * ASLOT, woB = sWrite * BSLOT;
        const int ko = (T + 2) * 32;
        const bool st = (T <= 29);

        bf16x8 bv[NFRAG];
#pragma unroll
        for (int p = 0; p < NPH; ++p) {
            if (p == 0) {
#pragma unroll
                for (int nf = 0; nf < NFRAG; ++nf)
                    bv[nf] = *(const bf16x8*)&sB[soB + (bl + nf * 16) * 32 + xs * 8];
            }
            bf16x8 af0 = *(const bf16x8*)&sA[soA + (al + (2 * p) * 16) * 32 + xs * 8];
            bf16x8 af1 = *(const bf16x8*)&sA[soA + (al + (2 * p + 1) * 16) * 32 + xs * 8];

            if (st) {
                if (p == 0) {
#pragma unroll
                    for (int i = 0; i < AGLD; ++i)
                        gload16(asrc + (size_t)i * 128 * D_DIM + ko, dA + woA + i * 4096);
                } else {
#pragma unroll
                    for (int i = 0; i < BGLD; ++i)
                        if ((i % (NPH - 1)) == p - 1)
                            gload16(bsrc + (size_t)i * 128 * D_DIM + ko, dB + woB + i * 4096);
                }
            }

            __builtin_amdgcn_s_barrier();
            asm volatile("s_waitcnt lgkmcnt(0)" ::: "memory");
            __builtin_amdgcn_s_setprio(1);
#pragma unroll
            for (int nf = 0; nf < NFRAG; ++nf) {
                acc[2 * p][nf]     = __builtin_amdgcn_mfma_f32_16x16x32_bf16(af0, bv[nf], acc[2 * p][nf], 0, 0, 0);
                acc[2 * p + 1][nf] = __builtin_amdgcn_mfma_f32_16x16x32_bf16(af1, bv[nf], acc[2 * p + 1][nf], 0, 0, 0);
            }
            __builtin_amdgcn_s_setprio(0);
            if (p == NPH - 1) {
                if (T <= 29)      vmwait<NGLD>();   // tile T+1 confirmed, T+2 in flight
                else if (T == 30) vmwait<0>();      // drain: tile 31 confirmed
            }
            __builtin_amdgcn_s_barrier();
        }

        sRead  = (sRead  == 2) ? 0 : sRead + 1;
        sWrite = (sWrite == 2) ? 0 : sWrite + 1;
    }
}

// ---------------------------------------------------------------------------
// Fused QKV GEMM: BM=256, BN=384 -> grid 32m x 8n = 256 blocks = 1.0 exact
// round, 153.6 FLOP/staged-byte. B^T = [Wq^T|Wk^T|Wv^T] contiguous; epilogue
// routes per 16-wide fragment. LDS 120KB (3-slot ring). XCD chunking:
// 4 m-tiles x all n per XCD -> A panel 2MB L2-resident.
// ---------------------------------------------------------------------------
__global__ __launch_bounds__(512, 2) void gemmqkv_k(const unsigned short* __restrict__ A,
                                                    const unsigned short* __restrict__ Bt,
                                                    unsigned short* __restrict__ qb,
                                                    unsigned short* __restrict__ kb,
                                                    unsigned short* __restrict__ vt)
{
    __shared__ unsigned short sA[3 * 2 * 4096];    // 48KB
    __shared__ unsigned short sB[3 * 3 * 4096];    // 72KB
    const int t = threadIdx.x;
    const int bid = blockIdx.x;                    // 256 = 8 XCD * 32
    const int wg = (bid & 7) * 32 + (bid >> 3);
    const int mt = wg >> 3, nt = wg & 7;
    const int m0 = mt * 256, n0 = nt * 384;

    f32x4 acc[8][6];
#pragma unroll
    for (int i = 0; i < 8; ++i)
#pragma unroll
        for (int j = 0; j < 6; ++j) acc[i][j] = (f32x4){0.f, 0.f, 0.f, 0.f};

    gemm_core<8, 6, 2, 3>(A, Bt, sA, sB, m0, n0, t, acc);

    const int lane = t & 63, wid = t >> 6;
    const int mm = lane & 15, quad = lane >> 4;
    const int wm = wid >> 2, wn = wid & 3;

#pragma unroll
    for (int nf = 0; nf < 6; ++nf) {
        const int c0 = n0 + wn * 96 + nf * 16;     // 16-aligned -> widx uniform
        const int widx = c0 >> 10, nl0 = c0 & 1023;
        if (widx == 2) {
            // V: write transposed per head (16-wide frag never crosses a head)
            const int h = nl0 >> 6, hd = (nl0 & 63) + mm;
#pragma unroll
            for (int mf = 0; mf < 8; ++mf) {
                int rglob = m0 + wm * 128 + mf * 16 + quad * 4;
                int bb = rglob >> 11, ss = rglob & (S_LEN - 1);
                union { unsigned short s[4]; unsigned long long ll; } pk;
#pragma unroll
                for (int r = 0; r < 4; ++r) pk.s[r] = f2bf(acc[mf][nf][r]);
                *(unsigned long long*)&vt[((size_t)(bb * NH + h) * HD + hd) * S_LEN + ss] = pk.ll;
            }
        } else {
            unsigned short* outp = widx ? kb : qb;
#pragma unroll
            for (int mf = 0; mf < 8; ++mf)
#pragma unroll
                for (int r = 0; r < 4; ++r)
                    outp[(size_t)(m0 + wm * 128 + mf * 16 + quad * 4 + r) * D_DIM +
                         nl0 + mm] = f2bf(acc[mf][nf][r]);
        }
    }
}

// ---------------------------------------------------------------------------
// Output GEMM: out_fp32 = ctx_bf16 * WoT^T. BM=128, BN=256 -> 64m x 4n =
// 256 blocks = 1.0 exact round. Same fine-phase core (2 phases x 8 MFMA).
// XCD chunking 8m x 4n: A 2MB + B 2MB both L2-resident per XCD.
// ---------------------------------------------------------------------------
__global__ __launch_bounds__(512, 2) void gemmo_k(const unsigned short* __restrict__ A,
                                                  const unsigned short* __restrict__ Bt,
                                                  float* __restrict__ C)
{
    __shared__ unsigned short sA[3 * 4096];        // 24KB
    __shared__ unsigned short sB[3 * 2 * 4096];    // 48KB
    const int t = threadIdx.x;
    const int bid = blockIdx.x;                    // 256 = 8 XCD * 32
    const int wg = (bid & 7) * 32 + (bid >> 3);
    const int mt = wg >> 2, nt = wg & 3;
    const int m0 = mt * 128, n0 = nt * 256;

    f32x4 acc[4][4];
#pragma unroll
    for (int i = 0; i < 4; ++i)
#pragma unroll
        for (int j = 0; j < 4; ++j) acc[i][j] = (f32x4){0.f, 0.f, 0.f, 0.f};

    gemm_core<4, 4, 1, 2>(A, Bt, sA, sB, m0, n0, t, acc);

    const int lane = t & 63, wid = t >> 6;
    const int mm = lane & 15, quad = lane >> 4;
    const int wm = wid >> 2, wn = wid & 3;

#pragma unroll
    for (int mf = 0; mf < 4; ++mf)
#pragma unroll
        for (int nf = 0; nf < 4; ++nf)
#pragma unroll
            for (int r = 0; r < 4; ++r)
                C[(size_t)(m0 + wm * 64 + mf * 16 + quad * 4 + r) * D_DIM +
                  n0 + wn * 64 + nf * 16 + mm] = acc[mf][nf][r];
}

// ---------------------------------------------------------------------------
// Fused causal flash attention: 32x32x16 MFMA + in-register P (T12), 4 waves
// x 32 q-rows (QBLK=128), ONE strip per block. R6 vs R7 showed identical
// per-work rate at 8 waves/CU with no pipe >45% -> latency-bound,
// grid-limited occupancy. This round: grid 1024 = 4 blocks/CU = 16 waves/CU
// (4/SIMD), ALL blocks resident (LDS 4x32KB=128KB, VGPR 72 <= 128 cap).
// Load balance by construction vs the mod-256 block->CU pattern:
// c=bid&255 picks (xcd, u, bh); j=bid>>8 picks the round; qt = 4j +
// (j odd ? 3-u : u) -> every CU-slot's 4 blocks have sum(qt)=30 (uniform 68
// work-units) and share the same bh (K/V L2/L1 reuse; bh XCD-clustered,
// R6-verified FETCH 146->25MB).
// ---------------------------------------------------------------------------
__global__ __launch_bounds__(256, 4) void attn_k(const unsigned short* __restrict__ Q,
                                                 const unsigned short* __restrict__ K,
                                                 const unsigned short* __restrict__ Vt,
                                                 unsigned short* __restrict__ ctx)
{
    __shared__ unsigned short sK [2][64 * 64];   // [buf][key][hd]   2x8KB
    __shared__ unsigned short sVT[2][64 * 64];   // [buf][hd][key]   2x8KB
    const int t = threadIdx.x;
    const int lane = t & 63, w = t >> 6;          // w = 0..3
    const int m5 = lane & 31, h = lane >> 5;
    const int m7 = m5 & 7;
    const int bid = blockIdx.x;                   // 1024
    const int c = bid & 255, j = bid >> 8;        // CU-slot, round
    const int xcd = c & 7, u = (c >> 3) & 3, bhl = c >> 5;
    const int bh = xcd * 8 + bhl;                 // 8 bh per XCD
    const int qt = 4 * j + ((j & 1) ? (3 - u) : u);   // sum over rounds = 30
    const int b = bh >> 4, hh = bh & 15;
    const size_t rowbase = (size_t)b * S_LEN;
    const int coff = hh * HD;
    const unsigned short* Vh = Vt + (size_t)bh * HD * S_LEN;

    // staging: thread covers rows sc and sc+32, chunk sj; (sc+32)&7 == sc&7
    const int sc = t >> 3, sj = t & 7;
    const int sg = (sj ^ (sc & 7)) * 8;           // XOR chunk swizzle

    u16x8 onesu;
#pragma unroll
    for (int jj = 0; jj < 8; ++jj) onesu[jj] = 0x3F80;   // bf16 1.0
    const bf16x8 ones = __builtin_bit_cast(bf16x8, onesu);

    const int q0 = qt * 128;
    const int qrw = q0 + w * 32;              // wave q base
    const int qr  = qrw + m5;                 // this lane's q-row (= MFMA col)

    // Q in regs: B[k=hd][col=q]: lane needs Q[qr][s*16 + h*8 + 0..7]
    bf16x8 qf[4];
#pragma unroll
    for (int s = 0; s < 4; ++s)
        qf[s] = *(const bf16x8*)(Q + (rowbase + qr) * D_DIM + coff + s * 16 + h * 8);

    f32x16 o0, o1, l16;
#pragma unroll
    for (int r = 0; r < 16; ++r) { o0[r] = 0.f; o1[r] = 0.f; l16[r] = 0.f; }

    const int nkt = 2 * qt + 2;

    // prologue: stage tile 0 -> buf 0
    gload16(K  + (rowbase + sc) * D_DIM + coff + sg,      (void*)&sK[0][t * 8]);
    gload16(K  + (rowbase + sc + 32) * D_DIM + coff + sg, (void*)&sK[0][2048 + t * 8]);
    gload16(Vh + (size_t)sc * S_LEN + sg,                 (void*)&sVT[0][t * 8]);
    gload16(Vh + (size_t)(sc + 32) * S_LEN + sg,          (void*)&sVT[0][2048 + t * 8]);

    for (int kt = 0; kt < nkt; ++kt) {
        const int buf = kt & 1;
        __syncthreads();   // buf's loads drained (issued a full phase ago)
        if (kt + 1 < nkt) {
            const int k1 = (kt + 1) * 64;
            gload16(K  + (rowbase + k1 + sc) * D_DIM + coff + sg,      (void*)&sK[1 - buf][t * 8]);
            gload16(K  + (rowbase + k1 + sc + 32) * D_DIM + coff + sg, (void*)&sK[1 - buf][2048 + t * 8]);
            gload16(Vh + (size_t)sc * S_LEN + k1 + sg,                 (void*)&sVT[1 - buf][t * 8]);
            gload16(Vh + (size_t)(sc + 32) * S_LEN + k1 + sg,          (void*)&sVT[1 - buf][2048 + t * 8]);
        }
        const int k0 = kt * 64;
        if (k0 > qrw + 31) continue;   // fully masked for this wave

        // S^T = K Q^T : A=K rows (key = kf*32 + m5), k=hd
        f32x16 s0, s1;
#pragma unroll
        for (int r = 0; r < 16; ++r) { s0[r] = 0.f; s1[r] = 0.f; }
        __builtin_amdgcn_s_setprio(1);
#pragma unroll
        for (int s = 0; s < 4; ++s) {
            const int sl = ((2 * s + h) ^ m7) * 8;
            bf16x8 ak0 = *(const bf16x8*)&sK[buf][m5 * 64 + sl];
            bf16x8 ak1 = *(const bf16x8*)&sK[buf][(32 + m5) * 64 + sl];
            s0 = __builtin_amdgcn_mfma_f32_32x32x16_bf16(ak0, qf[s], s0, 0, 0, 0);
            s1 = __builtin_amdgcn_mfma_f32_32x32x16_bf16(ak1, qf[s], s1, 0, 0, 0);
        }
        __builtin_amdgcn_s_setprio(0);

        // p = exp2(s) (wq pre-scaled), mask, pack to PV B-frags in regs.
        // Lane reg r holds key_local = (r&3)+8*(r>>2)+4h within kf block.
        const bool needmask = (k0 + 63) > qrw;
        bf16x8 pb[4];
#pragma unroll
        for (int kf = 0; kf < 2; ++kf) {
            unsigned pw[8];
#pragma unroll
            for (int jj = 0; jj < 8; ++jj) {
                float plo = __builtin_amdgcn_exp2f(kf ? s1[2 * jj] : s0[2 * jj]);
                float phi = __builtin_amdgcn_exp2f(kf ? s1[2 * jj + 1] : s0[2 * jj + 1]);
                if (needmask) {
                    const int kb_ = k0 + kf * 32 + 4 * h;
                    const int r0 = 2 * jj, r1 = 2 * jj + 1;
                    if (kb_ + (r0 & 3) + 8 * (r0 >> 2) > qr) plo = 0.f;
                    if (kb_ + (r1 & 3) + 8 * (r1 >> 2) > qr) phi = 0.f;
                }
                pw[jj] = cvtpk_bf16(plo, phi);
            }
            pl32swap(pw[0], pw[2]);
            pl32swap(pw[1], pw[3]);
            pl32swap(pw[4], pw[6]);
            pl32swap(pw[5], pw[7]);
            union { unsigned u4[4]; bf16x8 v; } f0, f1;
            f0.u4[0] = pw[0]; f0.u4[1] = pw[1]; f0.u4[2] = pw[2]; f0.u4[3] = pw[3];
            f1.u4[0] = pw[4]; f1.u4[1] = pw[5]; f1.u4[2] = pw[6]; f1.u4[3] = pw[7];
            pb[kf * 2 + 0] = f0.v;
            pb[kf * 2 + 1] = f1.v;
        }

        // O^T += V^T P^T ; l += ones P^T  (same quantized P as PV)
        __builtin_amdgcn_s_setprio(1);
#pragma unroll
        for (int s = 0; s < 4; ++s) {
            const int sl = ((2 * s + h) ^ m7) * 8;
            bf16x8 vf0 = *(const bf16x8*)&sVT[buf][m5 * 64 + sl];
            bf16x8 vf1 = *(const bf16x8*)&sVT[buf][(32 + m5) * 64 + sl];
            l16 = __builtin_amdgcn_mfma_f32_32x32x16_bf16(ones, pb[s], l16, 0, 0, 0);
            o0  = __builtin_amdgcn_mfma_f32_32x32x16_bf16(vf0,  pb[s], o0, 0, 0, 0);
            o1  = __builtin_amdgcn_mfma_f32_32x32x16_bf16(vf1,  pb[s], o1, 0, 0, 0);
        }
        __builtin_amdgcn_s_setprio(0);
    }

    // normalize and store: O^T[hd][q]: reg rg*4+r -> hd = hf*32 + 8*rg + 4h + r
    const float linv = 1.f / l16[0];
#pragma unroll
    for (int hf = 0; hf < 2; ++hf) {
#pragma unroll
        for (int rg = 0; rg < 4; ++rg) {
            union { unsigned short s4[4]; unsigned long long ll; } pk4;
#pragma unroll
            for (int r = 0; r < 4; ++r)
                pk4.s4[r] = f2bf((hf ? o1[rg * 4 + r] : o0[rg * 4 + r]) * linv);
            *(unsigned long long*)&ctx[(rowbase + qr) * D_DIM + coff + hf * 32 + 8 * rg + 4 * h] = pk4.ll;
        }
    }
}

extern "C" void kernel_launch(void* const* d_in, const int* in_sizes, int n_in,
                              void* d_out, int out_size, void* d_ws, size_t ws_size,
                              hipStream_t stream)
{
    const float* x  = (const float*)d_in[0];
    const float* wq = (const float*)d_in[1];
    const float* wk = (const float*)d_in[2];
    const float* wv = (const float*)d_in[3];
    const float* wo = (const float*)d_in[4];

    const size_t XE = (size_t)M_ROWS * D_DIM;   // 8M elems
    const size_t WE = (size_t)D_DIM * D_DIM;    // 1M elems
    unsigned short* ws  = (unsigned short*)d_ws;
    unsigned short* xbf = ws;
    unsigned short* wt0 = xbf + XE;
    unsigned short* wt1 = wt0 + WE;
    unsigned short* wt2 = wt1 + WE;
    unsigned short* wt3 = wt2 + WE;
    unsigned short* qb  = wt3 + WE;
    unsigned short* kb  = qb + XE;
    unsigned short* vt  = kb + XE;      // V stored transposed per head
    unsigned short* cb  = vt + XE;      // ~80 MB total

    prep_k<<<dim3(4096 + 1024), 256, 0, stream>>>(x, wq, wk, wv, wo,
                                                  xbf, wt0, wt1, wt2, wt3);

    gemmqkv_k<<<dim3(256), 512, 0, stream>>>(xbf, wt0, qb, kb, vt);

    attn_k<<<dim3(1024), 256, 0, stream>>>(qb, kb, vt, cb);

    gemmo_k<<<dim3(256), 512, 0, stream>>>(cb, wt3, (float*)d_out);
}